// Round 5
// baseline (277.073 us; speedup 1.0000x reference)
//
#include <hip/hip_runtime.h>
#include <hip/hip_bf16.h>
#include <math.h>

typedef __attribute__((ext_vector_type(8))) short short8;
typedef __attribute__((ext_vector_type(4))) float f32x4;

// ---------------- workspace layout (bytes) ----------------
#define W1P_OFF   0u          // 128*12*64*8 bf16 = 1,572,864 B
#define W2P_OFF   1572864u    // 128*8*64*8  bf16 = 1,048,576 B
#define W3P_OFF   2621440u
#define W4P_OFF   3670016u    // 128*8*256*8 bf16 = 4,194,304 B
#define EI_OFF    7864320u    // 128*2*32 f32 = 32,768 B
#define RECIP_OFF 7897088u    // 2048 f32
#define PART_OFF  7905280u    // 16*2048*256 f32 = 33,554,432 B
// total = 41,459,712 B

// output offsets (f32 elements)
#define OUT_C    0      // [2,1024,3]
#define OUT_D    6144   // [2,1024,1]
#define OUT_EI   8192   // [128,2,32]
#define OUT_ND   16384  // [128,2,3]
#define OUT_MEAN 17152  // [128,2,8]
#define OUT_STD  19200  // [128,2,8]

// ============ kernel 0: pack feature-field weights to bf16 B-fragment order ============
// packed layout per node: [kc][col][8] where k = kc*8+e  (lane reads 16B contiguous)
__global__ void pack_weights(const float* __restrict__ f1w, const float* __restrict__ f2w,
                             const float* __restrict__ f3w, const float* __restrict__ f4w,
                             __hip_bfloat16* __restrict__ w1p, __hip_bfloat16* __restrict__ w2p,
                             __hip_bfloat16* __restrict__ w3p, __hip_bfloat16* __restrict__ w4p) {
  int id = blockIdx.x * 256 + threadIdx.x;
  union { __hip_bfloat16 h[8]; int4 v; } u;
  if (id < 98304) {                       // W1: [n][12 kc][64 o], K=95 padded to 96
    int n = id / 768, r = id % 768, kc = r >> 6, o = r & 63;
    #pragma unroll
    for (int e = 0; e < 8; e++) {
      int k = kc * 8 + e;
      float val = (k < 95) ? f1w[((size_t)n * 95 + k) * 64 + o] : 0.f;
      u.h[e] = __float2bfloat16(val);
    }
    reinterpret_cast<int4*>(w1p)[id] = u.v;
  } else if (id < 163840) {               // W2: [n][8][64]
    int id2 = id - 98304;
    int n = id2 / 512, r = id2 % 512, kc = r >> 6, o = r & 63;
    #pragma unroll
    for (int e = 0; e < 8; e++)
      u.h[e] = __float2bfloat16(f2w[((size_t)n * 64 + kc * 8 + e) * 64 + o]);
    reinterpret_cast<int4*>(w2p)[id2] = u.v;
  } else if (id < 229376) {               // W3
    int id3 = id - 163840;
    int n = id3 / 512, r = id3 % 512, kc = r >> 6, o = r & 63;
    #pragma unroll
    for (int e = 0; e < 8; e++)
      u.h[e] = __float2bfloat16(f3w[((size_t)n * 64 + kc * 8 + e) * 64 + o]);
    reinterpret_cast<int4*>(w3p)[id3] = u.v;
  } else if (id < 491520) {               // W4: [n][8][256]
    int id4 = id - 229376;
    int n = id4 / 2048, r = id4 % 2048, kc = r >> 8, o = r & 255;
    #pragma unroll
    for (int e = 0; e < 8; e++)
      u.h[e] = __float2bfloat16(f4w[((size_t)n * 64 + kc * 8 + e) * 256 + o]);
    reinterpret_cast<int4*>(w4p)[id4] = u.v;
  }
}

// ============ kernel 1: encoder + decoder (f32 exact, tiny) ============
__global__ void encdec(const float* __restrict__ t_ped, const float* __restrict__ pose,
                       const float* __restrict__ ec1w, const float* __restrict__ ec1b,
                       const float* __restrict__ ec21w, const float* __restrict__ ec21b,
                       const float* __restrict__ ec22w, const float* __restrict__ ec22b,
                       const float* __restrict__ dc1w, const float* __restrict__ dc1b,
                       const float* __restrict__ dc21w, const float* __restrict__ dc21b,
                       const float* __restrict__ dc22w, const float* __restrict__ dc22b,
                       float* __restrict__ out, float* __restrict__ ei_ws) {
  __shared__ float enc_in[2][88];
  __shared__ float net[2][64];
  __shared__ float dec_in[2][80];
  __shared__ float dnet[2][64];
  int n = blockIdx.x, t = threadIdx.x;
  if (t < 32) { int b = t >> 4, i = t & 15; enc_in[b][i] = t_ped[b * 16 + i]; }
  for (int idx = t; idx < 144; idx += 64) {
    int b = idx / 72, i = idx - b * 72;
    float pv = pose[idx];
    enc_in[b][16 + i] = pv;
    dec_in[b][8 + i] = pv;
  }
  __syncthreads();
  { // net = relu(enc_in @ ec1_w + b)
    float a0 = ec1b[n * 64 + t], a1 = a0;
    const float* w = ec1w + (size_t)n * 88 * 64 + t;
    for (int i = 0; i < 88; i++) { float wv = w[i * 64]; a0 += enc_in[0][i] * wv; a1 += enc_in[1][i] * wv; }
    net[0][t] = fmaxf(a0, 0.f); net[1][t] = fmaxf(a1, 0.f);
  }
  __syncthreads();
  if (t < 32) { // mean (t<16) / std (t>=16)
    int isd = t >> 4, b = (t >> 3) & 1, o = t & 7;
    const float* w = (isd ? ec22w : ec21w) + (size_t)n * 64 * 8 + o;
    float acc = (isd ? ec22b : ec21b)[n * 8 + o];
    for (int i = 0; i < 64; i++) acc += net[b][i] * w[i * 8];
    if (isd) out[OUT_STD + (n * 2 + b) * 8 + o] = 1.f / (1.f + expf(-acc));
    else { out[OUT_MEAN + (n * 2 + b) * 8 + o] = acc; dec_in[b][o] = acc; }
  }
  __syncthreads();
  { // dnet = relu(dec_in @ dc1_w + b)
    float a0 = dc1b[n * 64 + t], a1 = a0;
    const float* w = dc1w + (size_t)n * 80 * 64 + t;
    for (int i = 0; i < 80; i++) { float wv = w[i * 64]; a0 += dec_in[0][i] * wv; a1 += dec_in[1][i] * wv; }
    dnet[0][t] = fmaxf(a0, 0.f); dnet[1][t] = fmaxf(a1, 0.f);
  }
  __syncthreads();
  { // ei (no activation)
    int b = t >> 5, o = t & 31;
    const float* w = dc21w + (size_t)n * 64 * 32 + o;
    float acc = dc21b[n * 32 + o];
    for (int i = 0; i < 64; i++) acc += dnet[b][i] * w[i * 32];
    out[OUT_EI + (n * 2 + b) * 32 + o] = acc;
    ei_ws[(n * 2 + b) * 32 + o] = acc;
  }
  if (t < 6) { // nodes_delta
    int b = t / 3, o = t - b * 3;
    const float* w = dc22w + (size_t)n * 64 * 3 + o;
    float acc = dc22b[n * 3 + o];
    for (int i = 0; i < 64; i++) acc += dnet[b][i] * w[i * 3];
    out[OUT_ND + (n * 2 + b) * 3 + o] = acc;
  }
}

// ============ kernel 1b: blend-weight normalizer ============
__global__ void bwsum(const float* __restrict__ bwt, float* __restrict__ recip) {
  int r = blockIdx.x * 256 + threadIdx.x;  // r = b*1024+v
  float s = 0.f;
  for (int n = 0; n < 128; n++) s += bwt[n * 2048 + r];
  recip[r] = 1.f / (s + 128.f * 1e-7f);
}

// ============ kernel 2: feature field (MFMA bf16) + partial blend ============
// v2: occupancy-first. grid = 16 node-groups x 64 row-tiles (32 rows), 1024 blocks.
// LDS only for A-side (x, h): ~15.9 KB. B-fragments (weights) read directly from
// packed global (L2-resident, 64 blocks/group share them). 4 waves = (row-tile rt x col-half ch).
__launch_bounds__(256, 4)
__global__ void feature_field(const float* __restrict__ coords, const int* __restrict__ mask,
                              const float* __restrict__ bwt,
                              const __hip_bfloat16* __restrict__ w1p, const __hip_bfloat16* __restrict__ w2p,
                              const __hip_bfloat16* __restrict__ w3p, const __hip_bfloat16* __restrict__ w4p,
                              const float* __restrict__ f1b, const float* __restrict__ f2b,
                              const float* __restrict__ f3b, const float* __restrict__ f4b,
                              const float* __restrict__ ei_ws, const float* __restrict__ recip,
                              float* __restrict__ part) {
  __shared__ __align__(16) __hip_bfloat16 xs[32][104];   // 6,656 B (stride 104: odd*8 -> no pow2 conflict)
  __shared__ __align__(16) __hip_bfloat16 hs[2][32][72]; // 9,216 B

  const int tid = threadIdx.x;
  const int g = blockIdx.x >> 6;          // node group 0..15
  const int tile = blockIdx.x & 63;       // row tile 0..63
  const int b = tile >> 5;
  const int v0 = (tile & 31) << 5;        // 32-row tiles
  const int lane = tid & 63;
  const int wv = tid >> 6;
  const int rt = wv >> 1;                 // row-tile half (0/1)
  const int ch = wv & 1;                  // col half (0/1)
  const int l16 = lane & 15;
  const int kg = lane >> 4;
  const int arow = rt * 16 + l16;         // A-fragment row (0..31)
  const int crow = rt * 16 + kg * 4;      // C-fragment row base (+r)

  const f32x4 zero4 = {0.f, 0.f, 0.f, 0.f};
  f32x4 pb[8];
  #pragma unroll
  for (int i = 0; i < 8; i++) pb[i] = zero4;

  // zero-pad cols 95..103 once (never overwritten by staging)
  for (int idx = tid; idx < 32 * 9; idx += 256) {
    int r = idx / 9, c = idx - r * 9;
    xs[r][95 + c] = __float2bfloat16(0.f);
  }

  for (int ni = 0; ni < 8; ni++) {
    const int n = (g << 3) + ni;
    // ---- stage x = [ei(32) | coords(63) | pad] as bf16; float4 coords loads ----
    {
      const float* cb = coords + ((size_t)((n << 1) + b) * 1024 + v0) * 63;
      const float4* cb4 = reinterpret_cast<const float4*>(cb);  // 16B-aligned: v0*63*4 = mult of 16
      for (int j = tid; j < 504; j += 256) {
        float4 v = cb4[j];
        int idx = j * 4;
        #pragma unroll
        for (int e = 0; e < 4; e++) {
          int ii = idx + e;
          int row = ii / 63, col = ii - row * 63;
          xs[row][32 + col] = __float2bfloat16(((const float*)&v)[e]);
        }
      }
      float eif = ei_ws[((n << 1) + b) * 32 + (tid & 31)];
      __hip_bfloat16 eib = __float2bfloat16(eif);
      int r0 = tid >> 5;  // 0..7
      #pragma unroll
      for (int k = 0; k < 4; k++) xs[r0 + k * 8][tid & 31] = eib;
    }
    __syncthreads();  // also orders next-node staging vs prior L4 hs reads

    const __hip_bfloat16* w1n = w1p + (size_t)n * 6144;
    const __hip_bfloat16* w2n = w2p + (size_t)n * 4096;
    const __hip_bfloat16* w3n = w3p + (size_t)n * 4096;
    const __hip_bfloat16* w4n = w4p + (size_t)n * 16384;

    // ---- L1: [32x96] @ [96x64]; wave covers nt = 2ch, 2ch+1 ----
    {
      short8 a[3];
      #pragma unroll
      for (int kt = 0; kt < 3; kt++)
        a[kt] = *reinterpret_cast<const short8*>(&xs[arow][kt * 32 + kg * 8]);
      #pragma unroll
      for (int nt2 = 0; nt2 < 2; nt2++) {
        int nt = ch * 2 + nt2;
        int col = nt * 16 + l16;
        f32x4 acc = zero4;
        #pragma unroll
        for (int kt = 0; kt < 3; kt++) {
          short8 bf = *reinterpret_cast<const short8*>(&w1n[((kt * 4 + kg) * 64 + col) * 8]);
          acc = __builtin_amdgcn_mfma_f32_16x16x32_bf16(a[kt], bf, acc, 0, 0, 0);
        }
        float bias = f1b[(n << 6) + col];
        #pragma unroll
        for (int r = 0; r < 4; r++)
          hs[0][crow + r][col] = __float2bfloat16(fmaxf(acc[r] + bias, 0.f));
      }
    }
    __syncthreads();
    // ---- L2: hs[0] -> hs[1] ----
    {
      short8 a[2];
      #pragma unroll
      for (int kt = 0; kt < 2; kt++)
        a[kt] = *reinterpret_cast<const short8*>(&hs[0][arow][kt * 32 + kg * 8]);
      #pragma unroll
      for (int nt2 = 0; nt2 < 2; nt2++) {
        int nt = ch * 2 + nt2;
        int col = nt * 16 + l16;
        f32x4 acc = zero4;
        #pragma unroll
        for (int kt = 0; kt < 2; kt++) {
          short8 bf = *reinterpret_cast<const short8*>(&w2n[((kt * 4 + kg) * 64 + col) * 8]);
          acc = __builtin_amdgcn_mfma_f32_16x16x32_bf16(a[kt], bf, acc, 0, 0, 0);
        }
        float bias = f2b[(n << 6) + col];
        #pragma unroll
        for (int r = 0; r < 4; r++)
          hs[1][crow + r][col] = __float2bfloat16(fmaxf(acc[r] + bias, 0.f));
      }
    }
    __syncthreads();
    // ---- L3: hs[1] -> hs[0] ----
    {
      short8 a[2];
      #pragma unroll
      for (int kt = 0; kt < 2; kt++)
        a[kt] = *reinterpret_cast<const short8*>(&hs[1][arow][kt * 32 + kg * 8]);
      #pragma unroll
      for (int nt2 = 0; nt2 < 2; nt2++) {
        int nt = ch * 2 + nt2;
        int col = nt * 16 + l16;
        f32x4 acc = zero4;
        #pragma unroll
        for (int kt = 0; kt < 2; kt++) {
          short8 bf = *reinterpret_cast<const short8*>(&w3n[((kt * 4 + kg) * 64 + col) * 8]);
          acc = __builtin_amdgcn_mfma_f32_16x16x32_bf16(a[kt], bf, acc, 0, 0, 0);
        }
        float bias = f3b[(n << 6) + col];
        #pragma unroll
        for (int r = 0; r < 4; r++)
          hs[0][crow + r][col] = __float2bfloat16(fmaxf(acc[r] + bias, 0.f));
      }
    }
    __syncthreads();
    // ---- L4: [32x64] @ [64x256], fused mask*blend-weight, accumulate partial ----
    // wave covers nt = ch*8 .. ch*8+7
    {
      short8 a[2];
      #pragma unroll
      for (int kt = 0; kt < 2; kt++)
        a[kt] = *reinterpret_cast<const short8*>(&hs[0][arow][kt * 32 + kg * 8]);
      float wrow[4];
      #pragma unroll
      for (int r = 0; r < 4; r++) {
        int gi = (b << 10) + v0 + crow + r;
        float bwv = (bwt[(n << 11) + gi] + 1e-7f) * recip[gi];
        wrow[r] = (mask[(n << 11) + gi] != 0) ? bwv : 0.f;
      }
      #pragma unroll
      for (int nti = 0; nti < 8; nti++) {
        int nt = ch * 8 + nti;
        int col = nt * 16 + l16;
        f32x4 acc = zero4;
        #pragma unroll
        for (int kt = 0; kt < 2; kt++) {
          short8 bf = *reinterpret_cast<const short8*>(&w4n[((kt * 4 + kg) * 256 + col) * 8]);
          acc = __builtin_amdgcn_mfma_f32_16x16x32_bf16(a[kt], bf, acc, 0, 0, 0);
        }
        float bias = f4b[(n << 8) + col];
        #pragma unroll
        for (int r = 0; r < 4; r++) {
          float fv = fmaxf(acc[r] + bias, 0.f);
          pb[nti][r] += wrow[r] * fv;
        }
      }
    }
    // no barrier here: next iteration's stage-sync orders xs writes vs L1 reads,
    // and L4 reads hs which staging doesn't touch.
  }
  // ---- write per-group partial blend ----
  {
    const int rbase = (b << 10) + v0 + crow;
    float* pr = part + ((size_t)(g * 2048 + rbase)) * 256 + l16;
    #pragma unroll
    for (int r = 0; r < 4; r++)
      #pragma unroll
      for (int nti = 0; nti < 8; nti++)
        pr[(size_t)r * 256 + (ch * 8 + nti) * 16] = pb[nti][r];
  }
}

// ============ kernel 3: reduce partials + NeRF head ============
__global__ void head(const float* __restrict__ part,
                     const float* __restrict__ c1w, const float* __restrict__ c1b,
                     const float* __restrict__ c2w, const float* __restrict__ c2b,
                     const float* __restrict__ d1w, const float* __restrict__ d1b,
                     float* __restrict__ out) {
  __shared__ float fbs[256];
  __shared__ float ncs[64];
  int row = blockIdx.x;  // 0..2047
  int t = threadIdx.x;
  float fb = 0.f;
  for (int gi = 0; gi < 16; gi++) fb += part[((size_t)gi * 2048 + row) * 256 + t];
  fbs[t] = fb;
  __syncthreads();
  if (t < 64) {
    float acc = c1b[t];
    for (int c = 0; c < 256; c++) acc += fbs[c] * c1w[c * 64 + t];
    ncs[t] = fmaxf(acc, 0.f);
  } else if (t >= 192) {  // one wave computes d
    int l = t - 192;
    float acc = 0.f;
    for (int c = l; c < 256; c += 64) acc += fbs[c] * d1w[c];
    for (int off = 32; off > 0; off >>= 1) acc += __shfl_down(acc, off);
    if (l == 0) out[OUT_D + row] = fmaxf(acc + d1b[0], 0.f);
  }
  __syncthreads();
  if (t < 3) {
    float acc = c2b[t];
    for (int i = 0; i < 64; i++) acc += ncs[i] * c2w[i * 3 + t];
    out[OUT_C + row * 3 + t] = acc;
  }
}

extern "C" void kernel_launch(void* const* d_in, const int* in_sizes, int n_in,
                              void* d_out, int out_size, void* d_ws, size_t ws_size,
                              hipStream_t stream) {
  (void)in_sizes; (void)n_in; (void)out_size; (void)ws_size;
  const float* t_ped  = (const float*)d_in[0];
  const float* pose   = (const float*)d_in[1];
  const float* coords = (const float*)d_in[2];
  const int*   maskp  = (const int*)d_in[3];
  const float* bwt    = (const float*)d_in[4];
  const float* ec1w = (const float*)d_in[5],  *ec1b = (const float*)d_in[6];
  const float* ec21w = (const float*)d_in[7], *ec21b = (const float*)d_in[8];
  const float* ec22w = (const float*)d_in[9], *ec22b = (const float*)d_in[10];
  const float* dc1w = (const float*)d_in[11], *dc1b = (const float*)d_in[12];
  const float* dc21w = (const float*)d_in[13], *dc21b = (const float*)d_in[14];
  const float* dc22w = (const float*)d_in[15], *dc22b = (const float*)d_in[16];
  const float* f1w = (const float*)d_in[17], *f1b = (const float*)d_in[18];
  const float* f2w = (const float*)d_in[19], *f2b = (const float*)d_in[20];
  const float* f3w = (const float*)d_in[21], *f3b = (const float*)d_in[22];
  const float* f4w = (const float*)d_in[23], *f4b = (const float*)d_in[24];
  const float* c1w = (const float*)d_in[25], *c1b = (const float*)d_in[26];
  const float* c2w = (const float*)d_in[27], *c2b = (const float*)d_in[28];
  const float* d1w = (const float*)d_in[29], *d1b = (const float*)d_in[30];
  float* out = (float*)d_out;
  char* ws = (char*)d_ws;
  __hip_bfloat16* w1p = (__hip_bfloat16*)(ws + W1P_OFF);
  __hip_bfloat16* w2p = (__hip_bfloat16*)(ws + W2P_OFF);
  __hip_bfloat16* w3p = (__hip_bfloat16*)(ws + W3P_OFF);
  __hip_bfloat16* w4p = (__hip_bfloat16*)(ws + W4P_OFF);
  float* ei_ws = (float*)(ws + EI_OFF);
  float* recip_ws = (float*)(ws + RECIP_OFF);
  float* part = (float*)(ws + PART_OFF);

  hipLaunchKernelGGL(pack_weights, dim3(1920), dim3(256), 0, stream,
                     f1w, f2w, f3w, f4w, w1p, w2p, w3p, w4p);
  hipLaunchKernelGGL(encdec, dim3(128), dim3(64), 0, stream,
                     t_ped, pose, ec1w, ec1b, ec21w, ec21b, ec22w, ec22b,
                     dc1w, dc1b, dc21w, dc21b, dc22w, dc22b, out, ei_ws);
  hipLaunchKernelGGL(bwsum, dim3(8), dim3(256), 0, stream, bwt, recip_ws);
  hipLaunchKernelGGL(feature_field, dim3(1024), dim3(256), 0, stream,
                     coords, maskp, bwt, w1p, w2p, w3p, w4p,
                     f1b, f2b, f3b, f4b, ei_ws, recip_ws, part);
  hipLaunchKernelGGL(head, dim3(2048), dim3(256), 0, stream,
                     part, c1w, c1b, c2w, c2b, d1w, d1b, out);
}

// Round 6
// 241.092 us; speedup vs baseline: 1.1492x; 1.1492x over previous
//
#include <hip/hip_runtime.h>
#include <hip/hip_bf16.h>
#include <math.h>

typedef __attribute__((ext_vector_type(8))) short short8;
typedef __attribute__((ext_vector_type(4))) float f32x4;

// ---------------- workspace layout (bytes) ----------------
#define W1P_OFF   0u          // 128*12*64*8 bf16 = 1,572,864 B
#define W2P_OFF   1572864u    // 128*8*64*8  bf16 = 1,048,576 B
#define W3P_OFF   2621440u
#define W4P_OFF   3670016u    // 128*8*256*8 bf16 = 4,194,304 B
#define EI_OFF    7864320u    // 128*2*32 f32 = 32,768 B
#define RECIP_OFF 7897088u    // 2048 f32
#define PART_OFF  7905280u    // 16*2048*256 f32 = 33,554,432 B
// total = 41,459,712 B

// output offsets (f32 elements)
#define OUT_C    0      // [2,1024,3]
#define OUT_D    6144   // [2,1024,1]
#define OUT_EI   8192   // [128,2,32]
#define OUT_ND   16384  // [128,2,3]
#define OUT_MEAN 17152  // [128,2,8]
#define OUT_STD  19200  // [128,2,8]

__device__ __forceinline__ short f2bs(float x) {
  __hip_bfloat16 h = __float2bfloat16(x);
  union { __hip_bfloat16 hh; short s; } u; u.hh = h; return u.s;
}

// ============ kernel 0: fused prep = pack_weights + encdec + bwsum ============
// blocks 0..1919: pack; 1920..1951: encdec (4 nodes each); 1952..1959: bwsum
__global__ void prep(const float* __restrict__ f1w, const float* __restrict__ f2w,
                     const float* __restrict__ f3w, const float* __restrict__ f4w,
                     __hip_bfloat16* __restrict__ w1p, __hip_bfloat16* __restrict__ w2p,
                     __hip_bfloat16* __restrict__ w3p, __hip_bfloat16* __restrict__ w4p,
                     const float* __restrict__ t_ped, const float* __restrict__ pose,
                     const float* __restrict__ ec1w, const float* __restrict__ ec1b,
                     const float* __restrict__ ec21w, const float* __restrict__ ec21b,
                     const float* __restrict__ ec22w, const float* __restrict__ ec22b,
                     const float* __restrict__ dc1w, const float* __restrict__ dc1b,
                     const float* __restrict__ dc21w, const float* __restrict__ dc21b,
                     const float* __restrict__ dc22w, const float* __restrict__ dc22b,
                     const float* __restrict__ bwt,
                     float* __restrict__ out, float* __restrict__ ei_ws,
                     float* __restrict__ recip) {
  const int bid = blockIdx.x;
  const int tid = threadIdx.x;
  if (bid < 1920) {
    // ---------------- pack ----------------
    int id = bid * 256 + tid;
    union { __hip_bfloat16 h[8]; int4 v; } u;
    if (id < 98304) {                       // W1: [n][12 kc][64 o], K=95 padded to 96
      int n = id / 768, r = id % 768, kc = r >> 6, o = r & 63;
      #pragma unroll
      for (int e = 0; e < 8; e++) {
        int k = kc * 8 + e;
        float val = (k < 95) ? f1w[((size_t)n * 95 + k) * 64 + o] : 0.f;
        u.h[e] = __float2bfloat16(val);
      }
      reinterpret_cast<int4*>(w1p)[id] = u.v;
    } else if (id < 163840) {               // W2: [n][8][64]
      int id2 = id - 98304;
      int n = id2 / 512, r = id2 % 512, kc = r >> 6, o = r & 63;
      #pragma unroll
      for (int e = 0; e < 8; e++)
        u.h[e] = __float2bfloat16(f2w[((size_t)n * 64 + kc * 8 + e) * 64 + o]);
      reinterpret_cast<int4*>(w2p)[id2] = u.v;
    } else if (id < 229376) {               // W3
      int id3 = id - 163840;
      int n = id3 / 512, r = id3 % 512, kc = r >> 6, o = r & 63;
      #pragma unroll
      for (int e = 0; e < 8; e++)
        u.h[e] = __float2bfloat16(f3w[((size_t)n * 64 + kc * 8 + e) * 64 + o]);
      reinterpret_cast<int4*>(w3p)[id3] = u.v;
    } else {                                // W4: [n][8][256]
      int id4 = id - 229376;
      int n = id4 / 2048, r = id4 % 2048, kc = r >> 8, o = r & 255;
      #pragma unroll
      for (int e = 0; e < 8; e++)
        u.h[e] = __float2bfloat16(f4w[((size_t)n * 64 + kc * 8 + e) * 256 + o]);
      reinterpret_cast<int4*>(w4p)[id4] = u.v;
    }
  } else if (bid < 1952) {
    // ---------------- encdec: 4 nodes per block ----------------
    __shared__ float enc_in[4][2][88];
    __shared__ float net[4][2][64];
    __shared__ float dec_in[4][2][80];
    __shared__ float dnet[4][2][64];
    const int sub = tid >> 6, t = tid & 63;
    const int n = (bid - 1920) * 4 + sub;
    if (t < 32) { int b = t >> 4, i = t & 15; enc_in[sub][b][i] = t_ped[b * 16 + i]; }
    for (int idx = t; idx < 144; idx += 64) {
      int b = idx / 72, i = idx - b * 72;
      float pv = pose[idx];
      enc_in[sub][b][16 + i] = pv;
      dec_in[sub][b][8 + i] = pv;
    }
    __syncthreads();
    { // net = relu(enc_in @ ec1_w + b)
      float a0 = ec1b[n * 64 + t], a1 = a0;
      const float* w = ec1w + (size_t)n * 88 * 64 + t;
      for (int i = 0; i < 88; i++) { float wv = w[i * 64]; a0 += enc_in[sub][0][i] * wv; a1 += enc_in[sub][1][i] * wv; }
      net[sub][0][t] = fmaxf(a0, 0.f); net[sub][1][t] = fmaxf(a1, 0.f);
    }
    __syncthreads();
    if (t < 32) { // mean (t<16) / std (t>=16)
      int isd = t >> 4, b = (t >> 3) & 1, o = t & 7;
      const float* w = (isd ? ec22w : ec21w) + (size_t)n * 64 * 8 + o;
      float acc = (isd ? ec22b : ec21b)[n * 8 + o];
      for (int i = 0; i < 64; i++) acc += net[sub][b][i] * w[i * 8];
      if (isd) out[OUT_STD + (n * 2 + b) * 8 + o] = 1.f / (1.f + expf(-acc));
      else { out[OUT_MEAN + (n * 2 + b) * 8 + o] = acc; dec_in[sub][b][o] = acc; }
    }
    __syncthreads();
    { // dnet = relu(dec_in @ dc1_w + b)
      float a0 = dc1b[n * 64 + t], a1 = a0;
      const float* w = dc1w + (size_t)n * 80 * 64 + t;
      for (int i = 0; i < 80; i++) { float wv = w[i * 64]; a0 += dec_in[sub][0][i] * wv; a1 += dec_in[sub][1][i] * wv; }
      dnet[sub][0][t] = fmaxf(a0, 0.f); dnet[sub][1][t] = fmaxf(a1, 0.f);
    }
    __syncthreads();
    { // ei (no activation)
      int b = t >> 5, o = t & 31;
      const float* w = dc21w + (size_t)n * 64 * 32 + o;
      float acc = dc21b[n * 32 + o];
      for (int i = 0; i < 64; i++) acc += dnet[sub][b][i] * w[i * 32];
      out[OUT_EI + (n * 2 + b) * 32 + o] = acc;
      ei_ws[(n * 2 + b) * 32 + o] = acc;
    }
    if (t < 6) { // nodes_delta
      int b = t / 3, o = t - b * 3;
      const float* w = dc22w + (size_t)n * 64 * 3 + o;
      float acc = dc22b[n * 3 + o];
      for (int i = 0; i < 64; i++) acc += dnet[sub][b][i] * w[i * 3];
      out[OUT_ND + (n * 2 + b) * 3 + o] = acc;
    }
  } else {
    // ---------------- bwsum ----------------
    int r = (bid - 1952) * 256 + tid;  // r = b*1024+v
    float s = 0.f;
    for (int n = 0; n < 128; n++) s += bwt[n * 2048 + r];
    recip[r] = 1.f / (s + 128.f * 1e-7f);
  }
}

// ============ kernel 2: feature field (MFMA bf16) — barrier-free, wave-independent ============
// grid = 16 groups x 32 tiles (64 rows) = 512 blocks; 4 waves/block, each wave owns
// 16 rows x 8 nodes end-to-end. No __syncthreads: per-wave LDS slice for the
// C-layout -> A-layout transpose between layers (same-wave LDS ops are processed
// in order; lgkmcnt(0) + wave_barrier guard the write->read edge).
__launch_bounds__(256, 2)
__global__ void feature_field(const float* __restrict__ coords, const int* __restrict__ mask,
                              const float* __restrict__ bwt,
                              const __hip_bfloat16* __restrict__ w1p, const __hip_bfloat16* __restrict__ w2p,
                              const __hip_bfloat16* __restrict__ w3p, const __hip_bfloat16* __restrict__ w4p,
                              const float* __restrict__ f1b, const float* __restrict__ f2b,
                              const float* __restrict__ f3b, const float* __restrict__ f4b,
                              const float* __restrict__ ei_ws, const float* __restrict__ recip,
                              float* __restrict__ part) {
  __shared__ __align__(16) __hip_bfloat16 hbuf[4][16][72];  // per-wave 2304B slices

  const int tid = threadIdx.x;
  const int wv = tid >> 6;
  const int lane = tid & 63;
  const int l16 = lane & 15;
  const int kg = lane >> 4;
  const int g = blockIdx.x >> 5;                 // node group 0..15
  const int row0 = (blockIdx.x & 31) * 64 + wv * 16;  // global row 0..2047
  const int b = row0 >> 10;
  const int v0 = row0 & 1023;

  const f32x4 zero4 = {0.f, 0.f, 0.f, 0.f};
  f32x4 pb[16];
  #pragma unroll
  for (int i = 0; i < 16; i++) pb[i] = zero4;

  for (int ni = 0; ni < 8; ni++) {
    const int n = (g << 3) + ni;
    // ---- A-fragments straight from global ----
    short8 a0, a1, a2;
    {
      const float* ep = ei_ws + ((n << 1) + b) * 32 + kg * 8;   // row-invariant
      #pragma unroll
      for (int e = 0; e < 8; e++) a0[e] = f2bs(ep[e]);
      const float* cp = coords + ((size_t)((n << 1) + b) * 1024 + v0 + l16) * 63;
      #pragma unroll
      for (int e = 0; e < 8; e++) a1[e] = f2bs(cp[kg * 8 + e]);
      #pragma unroll
      for (int e = 0; e < 8; e++) {
        int c = 32 + kg * 8 + e;
        a2[e] = (c < 63) ? f2bs(cp[c]) : (short)0;
      }
    }
    const __hip_bfloat16* w1n = w1p + (size_t)n * 6144;
    const __hip_bfloat16* w2n = w2p + (size_t)n * 4096;
    const __hip_bfloat16* w3n = w3p + (size_t)n * 4096;
    const __hip_bfloat16* w4n = w4p + (size_t)n * 16384;

    // ---- L1: [16x96] @ [96x64] ----
    {
      short8 bf[12];
      #pragma unroll
      for (int nt = 0; nt < 4; nt++)
        #pragma unroll
        for (int kt = 0; kt < 3; kt++)
          bf[nt * 3 + kt] = *reinterpret_cast<const short8*>(&w1n[((kt * 4 + kg) * 64 + nt * 16 + l16) * 8]);
      #pragma unroll
      for (int nt = 0; nt < 4; nt++) {
        f32x4 acc = zero4;
        acc = __builtin_amdgcn_mfma_f32_16x16x32_bf16(a0, bf[nt * 3 + 0], acc, 0, 0, 0);
        acc = __builtin_amdgcn_mfma_f32_16x16x32_bf16(a1, bf[nt * 3 + 1], acc, 0, 0, 0);
        acc = __builtin_amdgcn_mfma_f32_16x16x32_bf16(a2, bf[nt * 3 + 2], acc, 0, 0, 0);
        int col = nt * 16 + l16;
        float bias = f1b[(n << 6) + col];
        #pragma unroll
        for (int r = 0; r < 4; r++)
          hbuf[wv][kg * 4 + r][col] = __float2bfloat16(fmaxf(acc[r] + bias, 0.f));
      }
    }
    asm volatile("s_waitcnt lgkmcnt(0)");
    __builtin_amdgcn_wave_barrier();
    // ---- L2 ----
    {
      short8 ha[2];
      #pragma unroll
      for (int kt = 0; kt < 2; kt++)
        ha[kt] = *reinterpret_cast<const short8*>(&hbuf[wv][l16][kt * 32 + kg * 8]);
      __builtin_amdgcn_wave_barrier();
      short8 bf[8];
      #pragma unroll
      for (int nt = 0; nt < 4; nt++)
        #pragma unroll
        for (int kt = 0; kt < 2; kt++)
          bf[nt * 2 + kt] = *reinterpret_cast<const short8*>(&w2n[((kt * 4 + kg) * 64 + nt * 16 + l16) * 8]);
      #pragma unroll
      for (int nt = 0; nt < 4; nt++) {
        f32x4 acc = zero4;
        acc = __builtin_amdgcn_mfma_f32_16x16x32_bf16(ha[0], bf[nt * 2 + 0], acc, 0, 0, 0);
        acc = __builtin_amdgcn_mfma_f32_16x16x32_bf16(ha[1], bf[nt * 2 + 1], acc, 0, 0, 0);
        int col = nt * 16 + l16;
        float bias = f2b[(n << 6) + col];
        #pragma unroll
        for (int r = 0; r < 4; r++)
          hbuf[wv][kg * 4 + r][col] = __float2bfloat16(fmaxf(acc[r] + bias, 0.f));
      }
    }
    asm volatile("s_waitcnt lgkmcnt(0)");
    __builtin_amdgcn_wave_barrier();
    // ---- L3 ----
    {
      short8 ha[2];
      #pragma unroll
      for (int kt = 0; kt < 2; kt++)
        ha[kt] = *reinterpret_cast<const short8*>(&hbuf[wv][l16][kt * 32 + kg * 8]);
      __builtin_amdgcn_wave_barrier();
      short8 bf[8];
      #pragma unroll
      for (int nt = 0; nt < 4; nt++)
        #pragma unroll
        for (int kt = 0; kt < 2; kt++)
          bf[nt * 2 + kt] = *reinterpret_cast<const short8*>(&w3n[((kt * 4 + kg) * 64 + nt * 16 + l16) * 8]);
      #pragma unroll
      for (int nt = 0; nt < 4; nt++) {
        f32x4 acc = zero4;
        acc = __builtin_amdgcn_mfma_f32_16x16x32_bf16(ha[0], bf[nt * 2 + 0], acc, 0, 0, 0);
        acc = __builtin_amdgcn_mfma_f32_16x16x32_bf16(ha[1], bf[nt * 2 + 1], acc, 0, 0, 0);
        int col = nt * 16 + l16;
        float bias = f3b[(n << 6) + col];
        #pragma unroll
        for (int r = 0; r < 4; r++)
          hbuf[wv][kg * 4 + r][col] = __float2bfloat16(fmaxf(acc[r] + bias, 0.f));
      }
    }
    asm volatile("s_waitcnt lgkmcnt(0)");
    __builtin_amdgcn_wave_barrier();
    // ---- L4: [16x64] @ [64x256], fused mask*blend-weight ----
    {
      short8 ha[2];
      #pragma unroll
      for (int kt = 0; kt < 2; kt++)
        ha[kt] = *reinterpret_cast<const short8*>(&hbuf[wv][l16][kt * 32 + kg * 8]);
      __builtin_amdgcn_wave_barrier();
      float wrow[4];
      #pragma unroll
      for (int r = 0; r < 4; r++) {
        int gi = row0 + kg * 4 + r;
        float bwv = (bwt[(n << 11) + gi] + 1e-7f) * recip[gi];
        wrow[r] = (mask[(n << 11) + gi] != 0) ? bwv : 0.f;
      }
      #pragma unroll
      for (int c = 0; c < 4; c++) {
        short8 bf[8];
        #pragma unroll
        for (int nti = 0; nti < 4; nti++)
          #pragma unroll
          for (int kt = 0; kt < 2; kt++)
            bf[nti * 2 + kt] = *reinterpret_cast<const short8*>(&w4n[((kt * 4 + kg) * 256 + (c * 4 + nti) * 16 + l16) * 8]);
        #pragma unroll
        for (int nti = 0; nti < 4; nti++) {
          f32x4 acc = zero4;
          acc = __builtin_amdgcn_mfma_f32_16x16x32_bf16(ha[0], bf[nti * 2 + 0], acc, 0, 0, 0);
          acc = __builtin_amdgcn_mfma_f32_16x16x32_bf16(ha[1], bf[nti * 2 + 1], acc, 0, 0, 0);
          int nt = c * 4 + nti;
          float bias = f4b[(n << 8) + nt * 16 + l16];
          #pragma unroll
          for (int r = 0; r < 4; r++) {
            float fv = fmaxf(acc[r] + bias, 0.f);
            pb[nt][r] += wrow[r] * fv;
          }
        }
      }
    }
    __builtin_amdgcn_wave_barrier();  // keep next-node L1 writes after this node's L4 reads
  }
  // ---- write per-group partial blend ----
  {
    float* pr = part + ((size_t)(g * 2048 + row0 + kg * 4)) * 256 + l16;
    #pragma unroll
    for (int r = 0; r < 4; r++)
      #pragma unroll
      for (int nt = 0; nt < 16; nt++)
        pr[(size_t)r * 256 + nt * 16] = pb[nt][r];
  }
}

// ============ kernel 3: reduce partials + NeRF head ============
__global__ void head(const float* __restrict__ part,
                     const float* __restrict__ c1w, const float* __restrict__ c1b,
                     const float* __restrict__ c2w, const float* __restrict__ c2b,
                     const float* __restrict__ d1w, const float* __restrict__ d1b,
                     float* __restrict__ out) {
  __shared__ float fbs[256];
  __shared__ float ncs[64];
  int row = blockIdx.x;  // 0..2047
  int t = threadIdx.x;
  float fb = 0.f;
  for (int gi = 0; gi < 16; gi++) fb += part[((size_t)gi * 2048 + row) * 256 + t];
  fbs[t] = fb;
  __syncthreads();
  if (t < 64) {
    float acc = c1b[t];
    for (int c = 0; c < 256; c++) acc += fbs[c] * c1w[c * 64 + t];
    ncs[t] = fmaxf(acc, 0.f);
  } else if (t >= 192) {  // one wave computes d
    int l = t - 192;
    float acc = 0.f;
    for (int c = l; c < 256; c += 64) acc += fbs[c] * d1w[c];
    for (int off = 32; off > 0; off >>= 1) acc += __shfl_down(acc, off);
    if (l == 0) out[OUT_D + row] = fmaxf(acc + d1b[0], 0.f);
  }
  __syncthreads();
  if (t < 3) {
    float acc = c2b[t];
    for (int i = 0; i < 64; i++) acc += ncs[i] * c2w[i * 3 + t];
    out[OUT_C + row * 3 + t] = acc;
  }
}

extern "C" void kernel_launch(void* const* d_in, const int* in_sizes, int n_in,
                              void* d_out, int out_size, void* d_ws, size_t ws_size,
                              hipStream_t stream) {
  (void)in_sizes; (void)n_in; (void)out_size; (void)ws_size;
  const float* t_ped  = (const float*)d_in[0];
  const float* pose   = (const float*)d_in[1];
  const float* coords = (const float*)d_in[2];
  const int*   maskp  = (const int*)d_in[3];
  const float* bwt    = (const float*)d_in[4];
  const float* ec1w = (const float*)d_in[5],  *ec1b = (const float*)d_in[6];
  const float* ec21w = (const float*)d_in[7], *ec21b = (const float*)d_in[8];
  const float* ec22w = (const float*)d_in[9], *ec22b = (const float*)d_in[10];
  const float* dc1w = (const float*)d_in[11], *dc1b = (const float*)d_in[12];
  const float* dc21w = (const float*)d_in[13], *dc21b = (const float*)d_in[14];
  const float* dc22w = (const float*)d_in[15], *dc22b = (const float*)d_in[16];
  const float* f1w = (const float*)d_in[17], *f1b = (const float*)d_in[18];
  const float* f2w = (const float*)d_in[19], *f2b = (const float*)d_in[20];
  const float* f3w = (const float*)d_in[21], *f3b = (const float*)d_in[22];
  const float* f4w = (const float*)d_in[23], *f4b = (const float*)d_in[24];
  const float* c1w = (const float*)d_in[25], *c1b = (const float*)d_in[26];
  const float* c2w = (const float*)d_in[27], *c2b = (const float*)d_in[28];
  const float* d1w = (const float*)d_in[29], *d1b = (const float*)d_in[30];
  float* out = (float*)d_out;
  char* ws = (char*)d_ws;
  __hip_bfloat16* w1p = (__hip_bfloat16*)(ws + W1P_OFF);
  __hip_bfloat16* w2p = (__hip_bfloat16*)(ws + W2P_OFF);
  __hip_bfloat16* w3p = (__hip_bfloat16*)(ws + W3P_OFF);
  __hip_bfloat16* w4p = (__hip_bfloat16*)(ws + W4P_OFF);
  float* ei_ws = (float*)(ws + EI_OFF);
  float* recip_ws = (float*)(ws + RECIP_OFF);
  float* part = (float*)(ws + PART_OFF);

  hipLaunchKernelGGL(prep, dim3(1960), dim3(256), 0, stream,
                     f1w, f2w, f3w, f4w, w1p, w2p, w3p, w4p,
                     t_ped, pose, ec1w, ec1b, ec21w, ec21b, ec22w, ec22b,
                     dc1w, dc1b, dc21w, dc21b, dc22w, dc22b,
                     bwt, out, ei_ws, recip_ws);
  hipLaunchKernelGGL(feature_field, dim3(512), dim3(256), 0, stream,
                     coords, maskp, bwt, w1p, w2p, w3p, w4p,
                     f1b, f2b, f3b, f4b, ei_ws, recip_ws, part);
  hipLaunchKernelGGL(head, dim3(2048), dim3(256), 0, stream,
                     part, c1w, c1b, c2w, c2b, d1w, d1b, out);
}